// Round 7
// baseline (1366.006 us; speedup 1.0000x reference)
//
#include <hip/hip_runtime.h>

// ---------------------------------------------------------------------------
// LightGCN propagation: out = normalize(mean(emb, A emb, A^2 emb, A^3 emb))
// for two graphs (mashup: 100k nodes / 3.2M edges, api: 50k / 1.6M), D=64.
//
// Round-6: COLUMN-CHUNKED L2-RESIDENT SpMM.
//  - CSR sort key = row*NC + chunk(col), chunk sized so the gathered x-slice
//    (<=3.2MB fp16) fits every XCD's 4MB L2 (mashup NC=4, api NC=2).
//  - Each layer = NC sequential chunk dispatches; all CUs gather from the
//    same x-slice -> L2 hits instead of LLC round-trips. Partial sums RMW a
//    fp32 y32 buffer with NT accesses.
//  - Per-layer epilogue: acc_ml update + fp16 x_next (in-place) + final
//    normalize on the last layer.
//  - Graphs sequential (ws ~67MB: ev 25.6 + y32 25.6 + x0h 12.8 + keys 3.2).
//  - Scatter stays XCD-row-partitioned (round-4 form) with the new key.
// ---------------------------------------------------------------------------

#define EMB_DIM 64
#define UNRC 4
typedef unsigned long long ull;
typedef int v4i __attribute__((ext_vector_type(4)));

static inline int cdiv(long long a, long long b) { return (int)((a + b - 1) / b); }

// ----------------------------- CSR build -----------------------------------

__global__ void k_zero_i(int* __restrict__ p, int n) {
    int i = blockIdx.x * blockDim.x + threadIdx.x;
    if (i < n) p[i] = 0;
}

// histogram over key = row*NC + chunk(col)
__global__ void k_hist_key(const int* __restrict__ rows,
                           const int* __restrict__ cols, int ne, int NC,
                           unsigned cmul, int* __restrict__ cnt) {
    int n4 = ne >> 2;
    int i = blockIdx.x * blockDim.x + threadIdx.x;
    if (i < n4) {
        v4i r = __builtin_nontemporal_load((const v4i*)rows + i);
        v4i c = __builtin_nontemporal_load((const v4i*)cols + i);
        atomicAdd(&cnt[r.x * NC + (int)(((unsigned)c.x * cmul) >> 16)], 1);
        atomicAdd(&cnt[r.y * NC + (int)(((unsigned)c.y * cmul) >> 16)], 1);
        atomicAdd(&cnt[r.z * NC + (int)(((unsigned)c.z * cmul) >> 16)], 1);
        atomicAdd(&cnt[r.w * NC + (int)(((unsigned)c.w * cmul) >> 16)], 1);
    } else if (i == n4) {
        for (int t = n4 << 2; t < ne; ++t)
            atomicAdd(&cnt[rows[t] * NC +
                           (int)(((unsigned)cols[t] * cmul) >> 16)], 1);
    }
}

#define SCAN_B 256
#define SCAN_E 1024
__global__ void k_scan1(const int* __restrict__ in, int n,
                        int* __restrict__ out, int* __restrict__ bsums) {
    __shared__ int lds[SCAN_B];
    int t = threadIdx.x;
    int base = blockIdx.x * SCAN_E + t * 4;
    int v[4];
    int s = 0;
#pragma unroll
    for (int j = 0; j < 4; ++j) {
        v[j] = (base + j < n) ? in[base + j] : 0;
        s += v[j];
    }
    lds[t] = s;
    __syncthreads();
    for (int off = 1; off < SCAN_B; off <<= 1) {
        int x = (t >= off) ? lds[t - off] : 0;
        __syncthreads();
        lds[t] += x;
        __syncthreads();
    }
    int run = lds[t] - s;
    if (t == SCAN_B - 1) bsums[blockIdx.x] = lds[t];
#pragma unroll
    for (int j = 0; j < 4; ++j) {
        if (base + j < n) out[base + j] = run;
        run += v[j];
    }
}

__global__ void k_scan2(int* __restrict__ bsums, int nb) {
    __shared__ int lds[1024];
    int t = threadIdx.x;
    int v = (t < nb) ? bsums[t] : 0;
    lds[t] = v;
    __syncthreads();
    for (int off = 1; off < 1024; off <<= 1) {
        int x = (t >= off) ? lds[t - off] : 0;
        __syncthreads();
        lds[t] += x;
        __syncthreads();
    }
    if (t < nb) bsums[t] = lds[t] - v;
}

__global__ void k_scan3(int* __restrict__ kp, int* __restrict__ kpos,
                        const int* __restrict__ bsums, int n, int ne) {
    int i = blockIdx.x * blockDim.x + threadIdx.x;
    if (i < n) {
        int p = kp[i] + bsums[i >> 10];
        kp[i] = p;
        kpos[i] = p;
    }
    if (i == 0) kp[n] = ne;
}

// XCD-row-partitioned scatter with (row, chunk) key.
__global__ void k_scatter_key(const int* __restrict__ rows,
                              const int* __restrict__ cols,
                              const float* __restrict__ vals, int ne,
                              unsigned pmul, int NC, unsigned cmul,
                              int* __restrict__ kpos, ull* __restrict__ ev) {
    const int p = blockIdx.x & 7;
    const int bslot = blockIdx.x >> 3;
    const int nslot = gridDim.x >> 3;
    const int nb4 = ne >> 2;
    const v4i* rows4 = (const v4i*)rows;

    for (int g = bslot * blockDim.x + threadIdx.x; g < nb4;
         g += nslot * blockDim.x) {
        v4i r4 = __builtin_nontemporal_load(rows4 + g);
        int base = g << 2;
#pragma unroll
        for (int k = 0; k < 4; ++k) {
            int r = (k == 0) ? r4.x : (k == 1) ? r4.y : (k == 2) ? r4.z : r4.w;
            if ((int)(((unsigned)r * pmul) >> 16) == p) {
                int i = base + k;
                float v = __builtin_nontemporal_load(vals + i);
                int c = __builtin_nontemporal_load(cols + i);
                int key = r * NC + (int)(((unsigned)c * cmul) >> 16);
                ull pk = ((ull)__float_as_uint(v) << 32) | (unsigned)c;
                int pos = atomicAdd(&kpos[key], 1);
                ev[pos] = pk;
            }
        }
    }
    if (bslot == 0 && threadIdx.x == 0) {
        for (int i = nb4 << 2; i < ne; ++i) {
            int r = rows[i];
            if ((int)(((unsigned)r * pmul) >> 16) == p) {
                int c = cols[i];
                int key = r * NC + (int)(((unsigned)c * cmul) >> 16);
                ull pk = ((ull)__float_as_uint(vals[i]) << 32) | (unsigned)c;
                int pos = atomicAdd(&kpos[key], 1);
                ev[pos] = pk;
            }
        }
    }
}

// ----------------------------- fp16 convert --------------------------------

__global__ void k_tohalf(const float* __restrict__ s, _Float16* __restrict__ d,
                         int n) {
    int i = (blockIdx.x * blockDim.x + threadIdx.x) * 4;
    if (i < n) {
        float4 v = *reinterpret_cast<const float4*>(s + i);
        _Float16 h[4] = {(_Float16)v.x, (_Float16)v.y, (_Float16)v.z,
                         (_Float16)v.w};
        *reinterpret_cast<ushort4*>(d + i) = *reinterpret_cast<ushort4*>(h);
    }
}

// --------------------------- chunked CSR SpMM ------------------------------
// One wave per row, dual-edge (half h, sub): processes the row's edges whose
// col lies in chunk c (kp segment [row*NC+c, +1)). Gathers hit the 3.2MB
// L2-resident x-slice. Partial sums RMW y32 (NT).
__global__ void k_spmm_chunk(const ull* __restrict__ ev,
                             const int* __restrict__ kp, int NC, int c,
                             const _Float16* __restrict__ x,
                             float* __restrict__ y32, int nrows, int first) {
    int row = (int)((blockIdx.x * blockDim.x + threadIdx.x) >> 6);
    if (row >= nrows) return;
    int lane = threadIdx.x & 63;
    int h = lane >> 5;
    int sub = lane & 31;

    size_t kb = (size_t)row * NC + c;
    int s = kp[kb];
    int cnt = kp[kb + 1] - s;
    const ull* evr = ev + s;

    float ax[UNRC], ay[UNRC];
#pragma unroll
    for (int k = 0; k < UNRC; ++k) { ax[k] = 0.f; ay[k] = 0.f; }

    int j = 0;
    for (; j + 2 * UNRC <= cnt; j += 2 * UNRC) {
        ull p[UNRC];
#pragma unroll
        for (int k = 0; k < UNRC; ++k)
            p[k] = __builtin_nontemporal_load(evr + j + 2 * k + h);
#pragma unroll
        for (int k = 0; k < UNRC; ++k) {
            unsigned cc = (unsigned)p[k];
            unsigned xd = *reinterpret_cast<const unsigned*>(
                x + ((size_t)cc << 6) + (sub << 1));
            float v = __uint_as_float((unsigned)(p[k] >> 32));
            union { unsigned u; _Float16 f[2]; } cv;
            cv.u = xd;
            ax[k] = fmaf(v, (float)cv.f[0], ax[k]);
            ay[k] = fmaf(v, (float)cv.f[1], ay[k]);
        }
    }
    if (j < cnt) {
        ull p[UNRC];
        bool act[UNRC];
#pragma unroll
        for (int k = 0; k < UNRC; ++k) {
            int slot = j + 2 * k + h;
            act[k] = slot < cnt;
            p[k] = act[k] ? __builtin_nontemporal_load(evr + slot) : 0ull;
        }
#pragma unroll
        for (int k = 0; k < UNRC; ++k) {
            if (act[k]) {
                unsigned cc = (unsigned)p[k];
                unsigned xd = *reinterpret_cast<const unsigned*>(
                    x + ((size_t)cc << 6) + (sub << 1));
                float v = __uint_as_float((unsigned)(p[k] >> 32));
                union { unsigned u; _Float16 f[2]; } cv;
                cv.u = xd;
                ax[k] = fmaf(v, (float)cv.f[0], ax[k]);
                ay[k] = fmaf(v, (float)cv.f[1], ay[k]);
            }
        }
    }
    float tx = 0.f, ty = 0.f;
#pragma unroll
    for (int k = 0; k < UNRC; ++k) { tx += ax[k]; ty += ay[k]; }
    tx += __shfl_xor(tx, 32);
    ty += __shfl_xor(ty, 32);

    if (h == 0) {
        float* yp = y32 + ((size_t)row << 6) + (sub << 1);
        if (first) {
            __builtin_nontemporal_store(tx, yp);
            __builtin_nontemporal_store(ty, yp + 1);
        } else {
            float p0 = __builtin_nontemporal_load(yp);
            float p1 = __builtin_nontemporal_load(yp + 1);
            __builtin_nontemporal_store(p0 + tx, yp);
            __builtin_nontemporal_store(p1 + ty, yp + 1);
        }
    }
}

// Per-layer epilogue. mode 0: acc = emb + y, xn = fp16(y)
//                     mode 1: acc += y,      xn = fp16(y)
//                     mode 2: a = (acc+y)/4; normalize; acc = a/||a||
__global__ void k_epi(const float* __restrict__ y32, float* __restrict__ acc,
                      const float* __restrict__ emb, _Float16* __restrict__ xn,
                      int nrows, int mode) {
    int row = (int)((blockIdx.x * blockDim.x + threadIdx.x) >> 6);
    if (row >= nrows) return;
    int lane = threadIdx.x & 63;
    size_t idx = ((size_t)row << 6) | lane;

    float y = __builtin_nontemporal_load(y32 + idx);
    if (mode == 0) {
        acc[idx] = __builtin_nontemporal_load(emb + idx) + y;
        xn[idx] = (_Float16)y;
    } else if (mode == 1) {
        acc[idx] += y;
        xn[idx] = (_Float16)y;
    } else {
        float a = (acc[idx] + y) * 0.25f;
        float ss = a * a;
#pragma unroll
        for (int off = 32; off; off >>= 1) ss += __shfl_xor(ss, off);
        float nrm = fmaxf(sqrtf(ss), 1e-12f);
        acc[idx] = a / nrm;
    }
}

// ----------------------- fallback: atomic path -----------------------------

__global__ void k_copy2(const float4* __restrict__ src, float4* __restrict__ a,
                        float4* __restrict__ b, int n4) {
    int i = blockIdx.x * blockDim.x + threadIdx.x;
    if (i < n4) {
        float4 v = src[i];
        a[i] = v;
        b[i] = v;
    }
}

__global__ void k_zero(float4* __restrict__ p, int n4) {
    int i = blockIdx.x * blockDim.x + threadIdx.x;
    if (i < n4) p[i] = make_float4(0.f, 0.f, 0.f, 0.f);
}

__global__ void k_axpy(float4* __restrict__ acc, const float4* __restrict__ x,
                       int n4) {
    int i = blockIdx.x * blockDim.x + threadIdx.x;
    if (i < n4) {
        float4 a = acc[i];
        float4 v = x[i];
        a.x += v.x; a.y += v.y; a.z += v.z; a.w += v.w;
        acc[i] = a;
    }
}

__global__ void k_spmm_atomic(const int* __restrict__ rows,
                              const int* __restrict__ cols,
                              const float* __restrict__ vals,
                              const float* __restrict__ x,
                              float* __restrict__ y, int n_edges) {
    unsigned tid = blockIdx.x * blockDim.x + threadIdx.x;
    unsigned e = tid >> 4;
    if (e >= (unsigned)n_edges) return;
    int sub = tid & 15;
    int r = rows[e];
    int c = cols[e];
    float v = vals[e];
    const float4 xv =
        *reinterpret_cast<const float4*>(x + ((size_t)c << 6) + (sub << 2));
    float* yp = y + ((size_t)r << 6) + (sub << 2);
    unsafeAtomicAdd(yp + 0, v * xv.x);
    unsafeAtomicAdd(yp + 1, v * xv.y);
    unsafeAtomicAdd(yp + 2, v * xv.z);
    unsafeAtomicAdd(yp + 3, v * xv.w);
}

__global__ void k_normalize(float* __restrict__ out, int nrows) {
    int row = blockIdx.x * 4 + (threadIdx.x >> 6);
    if (row >= nrows) return;
    int lane = threadIdx.x & 63;
    size_t idx = ((size_t)row << 6) + lane;
    float v = out[idx] * 0.25f;
    float s = v * v;
#pragma unroll
    for (int off = 32; off; off >>= 1) s += __shfl_xor(s, off);
    float norm = fmaxf(sqrtf(s), 1e-12f);
    out[idx] = v / norm;
}

// ---------------------------------------------------------------------------

extern "C" void kernel_launch(void* const* d_in, const int* in_sizes, int n_in,
                              void* d_out, int out_size, void* d_ws,
                              size_t ws_size, hipStream_t stream) {
    const int* m_rows = (const int*)d_in[0];
    const int* m_cols = (const int*)d_in[1];
    const float* m_vals = (const float*)d_in[2];
    const int* a_rows = (const int*)d_in[3];
    const int* a_cols = (const int*)d_in[4];
    const float* a_vals = (const float*)d_in[5];
    const float* m_emb = (const float*)d_in[6];
    const float* a_emb = (const float*)d_in[7];

    int ne_m = in_sizes[0];
    int ne_a = in_sizes[3];
    int nm = in_sizes[6] / EMB_DIM;
    int na = in_sizes[7] / EMB_DIM;

    size_t elems_m = (size_t)nm * EMB_DIM;
    int nmax = nm > na ? nm : na;
    int nemax = ne_m > ne_a ? ne_m : ne_a;
    float* out_m = (float*)d_out;
    float* out_a = out_m + elems_m;

    // chunk counts: x-slice (n*128B / NC) must fit ~3.2MB per-XCD L2 budget
    int NC_m = cdiv((long long)nm * 128, 3355443);
    int NC_a = cdiv((long long)na * 128, 3355443);
    int nkmax = nm * NC_m > na * NC_a ? nm * NC_m : na * NC_a;

    // ws layout (graphs run sequentially; everything reused)
    char* w = (char*)d_ws;
    ull* ev = (ull*)w;           w += (size_t)nemax * sizeof(ull);
    float* y32 = (float*)w;      w += (size_t)nmax * EMB_DIM * sizeof(float);
    _Float16* x0h = (_Float16*)w; w += (size_t)nmax * EMB_DIM * sizeof(_Float16);
    int* kp = (int*)w;           w += ((size_t)nkmax + 1) * sizeof(int);
    int* kpos = (int*)w;         w += (size_t)nkmax * sizeof(int);
    int* bsums = (int*)w;        w += 1024 * sizeof(int);
    size_t need = (size_t)(w - (char*)d_ws);

    if (ws_size >= need) {
        auto run_graph = [&](const int* rows, const int* cols,
                             const float* vals, const float* emb, float* out,
                             int n, int ne, int NC) {
            int nk = n * NC;
            unsigned cmul = (unsigned)(((unsigned long long)NC << 16) / (unsigned)n);
            unsigned pmul = (unsigned)(((unsigned long long)8 << 16) / (unsigned)n);

            // ---- build (row, chunk)-sorted CSR ----
            k_zero_i<<<cdiv(nk, 256), 256, 0, stream>>>(kpos, nk);
            k_hist_key<<<cdiv((ne >> 2) + 1, 256), 256, 0, stream>>>(
                rows, cols, ne, NC, cmul, kpos);
            int nsb = cdiv(nk, SCAN_E);
            k_scan1<<<nsb, SCAN_B, 0, stream>>>(kpos, nk, kp, bsums);
            k_scan2<<<1, 1024, 0, stream>>>(bsums, nsb);
            k_scan3<<<cdiv(nk, 256), 256, 0, stream>>>(kp, kpos, bsums, nk, ne);
            k_scatter_key<<<2048, 256, 0, stream>>>(rows, cols, vals, ne, pmul,
                                                    NC, cmul, kpos, ev);
            // ---- fp16 source ----
            int nel = n * EMB_DIM;
            k_tohalf<<<cdiv(nel / 4, 256), 256, 0, stream>>>(emb, x0h, nel);
            // ---- 3 layers, NC chunk passes each ----
            int g = cdiv(n, 4);
            for (int l = 0; l < 3; ++l) {
                for (int c = 0; c < NC; ++c)
                    k_spmm_chunk<<<g, 256, 0, stream>>>(ev, kp, NC, c, x0h,
                                                        y32, n, c == 0);
                int mode = (l == 0) ? 0 : (l == 2 ? 2 : 1);
                k_epi<<<g, 256, 0, stream>>>(y32, out, emb, x0h, n, mode);
            }
        };
        run_graph(m_rows, m_cols, m_vals, m_emb, out_m, nm, ne_m, NC_m);
        run_graph(a_rows, a_cols, a_vals, a_emb, out_a, na, ne_a, NC_a);
        return;
    }

    // Fallback: round-0 atomic path.
    float* fb0 = (float*)d_ws;
    float* fb1 = fb0 + elems_m;
    auto run_atomic = [&](const int* rows, const int* cols, const float* vals,
                          const float* emb, float* out, int nrows,
                          int nedges) {
        size_t n = (size_t)nrows * EMB_DIM;
        int n4 = (int)(n / 4);
        int eg = cdiv(n4, 256);
        k_copy2<<<eg, 256, 0, stream>>>((const float4*)emb, (float4*)out,
                                        (float4*)fb0, n4);
        float* cur = fb0;
        float* nxt = fb1;
        int spmm_grid = cdiv((long long)nedges * 16, 256);
        for (int l = 0; l < 3; ++l) {
            k_zero<<<eg, 256, 0, stream>>>((float4*)nxt, n4);
            k_spmm_atomic<<<spmm_grid, 256, 0, stream>>>(rows, cols, vals, cur,
                                                         nxt, nedges);
            k_axpy<<<eg, 256, 0, stream>>>((float4*)out, (const float4*)nxt,
                                           n4);
            float* t = cur; cur = nxt; nxt = t;
        }
        k_normalize<<<cdiv(nrows, 4), 256, 0, stream>>>(out, nrows);
    };
    run_atomic(m_rows, m_cols, m_vals, m_emb, out_m, nm, ne_m);
    run_atomic(a_rows, a_cols, a_vals, a_emb, out_a, na, ne_a);
}

// Round 8
// 969.899 us; speedup vs baseline: 1.4084x; 1.4084x over previous
//
#include <hip/hip_runtime.h>

// ---------------------------------------------------------------------------
// LightGCN propagation: out = normalize(mean(emb, A emb, A^2 emb, A^3 emb))
// for two graphs (mashup: 100k nodes / 3.2M edges, api: 50k / 1.6M), D=64.
//
// Round-7 = round-5 structure (its 961us beat round-6's chunked 1366us)
// with QUAD-EDGE SpMM:
//  - lane = (quarter q, sub); quarter handles every-4th edge; lane gathers
//    4 fp16 dims (8B ull load; 16 lanes x 8B = 128B per edge row).
//    UNR=8 -> 32 edges (4KB) in flight per wave, 2x round-5's MLP.
//  - quarter-combine via shfl_xor(16) + shfl_xor(32); float4 epilogue.
//  - Merged CSR build + XCD-partitioned scatter unchanged from round-5.
// ---------------------------------------------------------------------------

#define EMB_DIM 64
#define UNR 8
typedef unsigned long long ull;
typedef int v4i __attribute__((ext_vector_type(4)));

static inline int cdiv(long long a, long long b) { return (int)((a + b - 1) / b); }

// ----------------------------- CSR build -----------------------------------

__global__ void k_zero2(int* __restrict__ pm, int nm_, int* __restrict__ pa,
                        int na_) {
    int i = blockIdx.x * blockDim.x + threadIdx.x;
    if (i < nm_) pm[i] = 0;
    else if (i < nm_ + na_) pa[i - nm_] = 0;
}

// merged vectorized histogram: 4 edges per thread.
__global__ void k_hist2(const int* __restrict__ rm, int nem,
                        int* __restrict__ posm, const int* __restrict__ ra,
                        int nea, int* __restrict__ posa) {
    int nm4 = nem >> 2, na4 = nea >> 2;
    int i = blockIdx.x * blockDim.x + threadIdx.x;
    if (i < nm4) {
        v4i r = __builtin_nontemporal_load((const v4i*)rm + i);
        atomicAdd(&posm[r.x], 1);
        atomicAdd(&posm[r.y], 1);
        atomicAdd(&posm[r.z], 1);
        atomicAdd(&posm[r.w], 1);
    } else if (i < nm4 + na4) {
        v4i r = __builtin_nontemporal_load((const v4i*)ra + (i - nm4));
        atomicAdd(&posa[r.x], 1);
        atomicAdd(&posa[r.y], 1);
        atomicAdd(&posa[r.z], 1);
        atomicAdd(&posa[r.w], 1);
    } else if (i == nm4 + na4) {
        for (int t = nm4 << 2; t < nem; ++t) atomicAdd(&posm[rm[t]], 1);
        for (int t = na4 << 2; t < nea; ++t) atomicAdd(&posa[ra[t]], 1);
    }
}

#define SCAN_B 256
#define SCAN_E 1024
__global__ void k_scan1(const int* __restrict__ in, int n,
                        int* __restrict__ out, int* __restrict__ bsums) {
    __shared__ int lds[SCAN_B];
    int t = threadIdx.x;
    int base = blockIdx.x * SCAN_E + t * 4;
    int v[4];
    int s = 0;
#pragma unroll
    for (int j = 0; j < 4; ++j) {
        v[j] = (base + j < n) ? in[base + j] : 0;
        s += v[j];
    }
    lds[t] = s;
    __syncthreads();
    for (int off = 1; off < SCAN_B; off <<= 1) {
        int x = (t >= off) ? lds[t - off] : 0;
        __syncthreads();
        lds[t] += x;
        __syncthreads();
    }
    int run = lds[t] - s;
    if (t == SCAN_B - 1) bsums[blockIdx.x] = lds[t];
#pragma unroll
    for (int j = 0; j < 4; ++j) {
        if (base + j < n) out[base + j] = run;
        run += v[j];
    }
}

__global__ void k_scan2(int* __restrict__ bsums, int nb) {
    __shared__ int lds[1024];
    int t = threadIdx.x;
    int v = (t < nb) ? bsums[t] : 0;
    lds[t] = v;
    __syncthreads();
    for (int off = 1; off < 1024; off <<= 1) {
        int x = (t >= off) ? lds[t - off] : 0;
        __syncthreads();
        lds[t] += x;
        __syncthreads();
    }
    if (t < nb) bsums[t] = lds[t] - v;
}

__global__ void k_scan3(int* __restrict__ row_ptr, int* __restrict__ row_pos,
                        const int* __restrict__ bsums, int n, int ne) {
    int i = blockIdx.x * blockDim.x + threadIdx.x;
    if (i < n) {
        int p = row_ptr[i] + bsums[i >> 10];
        row_ptr[i] = p;
        row_pos[i] = p;
    }
    if (i == 0) row_ptr[n] = ne;
}

// Merged XCD-partitioned scatter: blocks [0,bm) -> mashup, [bm,grid) -> api.
__global__ void k_scatter2(const int* __restrict__ rm,
                           const int* __restrict__ cm,
                           const float* __restrict__ vm, int nem,
                           unsigned pmulm, int* __restrict__ posm,
                           ull* __restrict__ evm, const int* __restrict__ ra,
                           const int* __restrict__ ca,
                           const float* __restrict__ va, int nea,
                           unsigned pmula, int* __restrict__ posa,
                           ull* __restrict__ eva, int bm) {
    const int p = blockIdx.x & 7;
    const bool is_m = (int)blockIdx.x < bm;
    const int b = is_m ? blockIdx.x : blockIdx.x - bm;
    const int nslot = (is_m ? bm : (int)gridDim.x - bm) >> 3;
    const int bslot = b >> 3;

    const int* rows = is_m ? rm : ra;
    const int* cols = is_m ? cm : ca;
    const float* vals = is_m ? vm : va;
    const int ne = is_m ? nem : nea;
    const unsigned pmul = is_m ? pmulm : pmula;
    int* row_pos = is_m ? posm : posa;
    ull* ev = is_m ? evm : eva;

    const int nb4 = ne >> 2;
    const v4i* rows4 = (const v4i*)rows;

    for (int g = bslot * blockDim.x + threadIdx.x; g < nb4;
         g += nslot * blockDim.x) {
        v4i r4 = __builtin_nontemporal_load(rows4 + g);
        int base = g << 2;
#pragma unroll
        for (int k = 0; k < 4; ++k) {
            int r = (k == 0) ? r4.x : (k == 1) ? r4.y : (k == 2) ? r4.z : r4.w;
            if ((int)(((unsigned)r * pmul) >> 16) == p) {
                int i = base + k;
                float v = __builtin_nontemporal_load(vals + i);
                int c = __builtin_nontemporal_load(cols + i);
                ull pk = ((ull)__float_as_uint(v) << 32) | (unsigned)c;
                int pos = atomicAdd(&row_pos[r], 1);
                ev[pos] = pk;
            }
        }
    }
    if (bslot == 0 && threadIdx.x == 0) {
        for (int i = nb4 << 2; i < ne; ++i) {
            int r = rows[i];
            if ((int)(((unsigned)r * pmul) >> 16) == p) {
                ull pk = ((ull)__float_as_uint(vals[i]) << 32) |
                         (unsigned)cols[i];
                int pos = atomicAdd(&row_pos[r], 1);
                ev[pos] = pk;
            }
        }
    }
}

// ----------------------------- fp16 convert --------------------------------

__global__ void k_tohalf(const float* __restrict__ s, _Float16* __restrict__ d,
                         int n) {
    int i = (blockIdx.x * blockDim.x + threadIdx.x) * 4;
    if (i < n) {
        float4 v = *reinterpret_cast<const float4*>(s + i);
        _Float16 h[4] = {(_Float16)v.x, (_Float16)v.y, (_Float16)v.z,
                         (_Float16)v.w};
        *reinterpret_cast<ushort4*>(d + i) = *reinterpret_cast<ushort4*>(h);
    }
}

// ------------------------- quad-edge CSR SpMM ------------------------------
// One wave per row. lane = (q = lane>>4, sub = lane&15). Quarter q processes
// edges with slot%4==q; lane gathers dims (4sub..4sub+3) as one 8B load.
// 4 edges per load instruction -> 32 edges in flight at UNR=8.
// Quarter-combine: shfl_xor(16) + shfl_xor(32).
//   FIRST:  acc = emb_row + sum ; nxt = (fp16)sum
//   middle: acc += sum          ; nxt = (fp16)sum
//   LAST:   a = (acc+sum)/4 ; normalize ; acc = a/||a||
template <bool FIRST, bool LAST>
__global__ void k_spmm_quad(const ull* __restrict__ ev,
                            const int* __restrict__ row_ptr,
                            const _Float16* __restrict__ x,
                            _Float16* __restrict__ nxt,
                            float* __restrict__ acc,
                            const float* __restrict__ emb, int nrows) {
    int row = (int)((blockIdx.x * blockDim.x + threadIdx.x) >> 6);
    if (row >= nrows) return;
    int lane = threadIdx.x & 63;
    int q = lane >> 4;
    int sub = lane & 15;

    int s = row_ptr[row];
    int cnt = row_ptr[row + 1] - s;
    const ull* evr = ev + s;

    float a0[UNR], a1[UNR], a2[UNR], a3[UNR];
#pragma unroll
    for (int k = 0; k < UNR; ++k) {
        a0[k] = 0.f; a1[k] = 0.f; a2[k] = 0.f; a3[k] = 0.f;
    }

    int j = 0;
    for (; j + 4 * UNR <= cnt; j += 4 * UNR) {
        ull p[UNR];
#pragma unroll
        for (int k = 0; k < UNR; ++k)
            p[k] = __builtin_nontemporal_load(evr + j + 4 * k + q);
#pragma unroll
        for (int k = 0; k < UNR; ++k) {
            unsigned c = (unsigned)p[k];
            ull xd = *reinterpret_cast<const ull*>(
                x + ((size_t)c << 6) + (sub << 2));
            float v = __uint_as_float((unsigned)(p[k] >> 32));
            union { ull u; _Float16 f[4]; } cv;
            cv.u = xd;
            a0[k] = fmaf(v, (float)cv.f[0], a0[k]);
            a1[k] = fmaf(v, (float)cv.f[1], a1[k]);
            a2[k] = fmaf(v, (float)cv.f[2], a2[k]);
            a3[k] = fmaf(v, (float)cv.f[3], a3[k]);
        }
    }
    if (j < cnt) {
        ull p[UNR];
        bool act[UNR];
#pragma unroll
        for (int k = 0; k < UNR; ++k) {
            int slot = j + 4 * k + q;
            act[k] = slot < cnt;
            p[k] = act[k] ? __builtin_nontemporal_load(evr + slot) : 0ull;
        }
#pragma unroll
        for (int k = 0; k < UNR; ++k) {
            if (act[k]) {
                unsigned c = (unsigned)p[k];
                ull xd = *reinterpret_cast<const ull*>(
                    x + ((size_t)c << 6) + (sub << 2));
                float v = __uint_as_float((unsigned)(p[k] >> 32));
                union { ull u; _Float16 f[4]; } cv;
                cv.u = xd;
                a0[k] = fmaf(v, (float)cv.f[0], a0[k]);
                a1[k] = fmaf(v, (float)cv.f[1], a1[k]);
                a2[k] = fmaf(v, (float)cv.f[2], a2[k]);
                a3[k] = fmaf(v, (float)cv.f[3], a3[k]);
            }
        }
    }
    float t0 = 0.f, t1 = 0.f, t2 = 0.f, t3 = 0.f;
#pragma unroll
    for (int k = 0; k < UNR; ++k) {
        t0 += a0[k]; t1 += a1[k]; t2 += a2[k]; t3 += a3[k];
    }
    // combine the 4 quarters
    t0 += __shfl_xor(t0, 16); t0 += __shfl_xor(t0, 32);
    t1 += __shfl_xor(t1, 16); t1 += __shfl_xor(t1, 32);
    t2 += __shfl_xor(t2, 16); t2 += __shfl_xor(t2, 32);
    t3 += __shfl_xor(t3, 16); t3 += __shfl_xor(t3, 32);
    // every lane now holds the full row sums for dims (4sub..4sub+3)

    size_t base = ((size_t)row << 6) + (sub << 2);
    if (FIRST || !LAST) {
        if (q == 0) {
            float4 prev;
            if (FIRST)
                prev = *reinterpret_cast<const float4*>(emb + base);
            else
                prev = *reinterpret_cast<const float4*>(acc + base);
            float4 o = make_float4(prev.x + t0, prev.y + t1, prev.z + t2,
                                   prev.w + t3);
            *reinterpret_cast<float4*>(acc + base) = o;
            union { _Float16 f[4]; ull u; } h;
            h.f[0] = (_Float16)t0; h.f[1] = (_Float16)t1;
            h.f[2] = (_Float16)t2; h.f[3] = (_Float16)t3;
            *reinterpret_cast<ull*>(nxt + base) = h.u;
        }
    } else {
        float4 a2v = *reinterpret_cast<const float4*>(acc + base);
        float b0 = (a2v.x + t0) * 0.25f;
        float b1 = (a2v.y + t1) * 0.25f;
        float b2 = (a2v.z + t2) * 0.25f;
        float b3 = (a2v.w + t3) * 0.25f;
        float ss = b0 * b0 + b1 * b1 + b2 * b2 + b3 * b3;
#pragma unroll
        for (int off = 8; off; off >>= 1) ss += __shfl_xor(ss, off);
        float nrm = fmaxf(sqrtf(ss), 1e-12f);
        if (q == 0) {
            float4 o = make_float4(b0 / nrm, b1 / nrm, b2 / nrm, b3 / nrm);
            *reinterpret_cast<float4*>(acc + base) = o;
        }
    }
}

// ----------------------- fallback: atomic path -----------------------------

__global__ void k_copy2(const float4* __restrict__ src, float4* __restrict__ a,
                        float4* __restrict__ b, int n4) {
    int i = blockIdx.x * blockDim.x + threadIdx.x;
    if (i < n4) {
        float4 v = src[i];
        a[i] = v;
        b[i] = v;
    }
}

__global__ void k_zero(float4* __restrict__ p, int n4) {
    int i = blockIdx.x * blockDim.x + threadIdx.x;
    if (i < n4) p[i] = make_float4(0.f, 0.f, 0.f, 0.f);
}

__global__ void k_axpy(float4* __restrict__ acc, const float4* __restrict__ x,
                       int n4) {
    int i = blockIdx.x * blockDim.x + threadIdx.x;
    if (i < n4) {
        float4 a = acc[i];
        float4 v = x[i];
        a.x += v.x; a.y += v.y; a.z += v.z; a.w += v.w;
        acc[i] = a;
    }
}

__global__ void k_spmm_atomic(const int* __restrict__ rows,
                              const int* __restrict__ cols,
                              const float* __restrict__ vals,
                              const float* __restrict__ x,
                              float* __restrict__ y, int n_edges) {
    unsigned tid = blockIdx.x * blockDim.x + threadIdx.x;
    unsigned e = tid >> 4;
    if (e >= (unsigned)n_edges) return;
    int sub = tid & 15;
    int r = rows[e];
    int c = cols[e];
    float v = vals[e];
    const float4 xv =
        *reinterpret_cast<const float4*>(x + ((size_t)c << 6) + (sub << 2));
    float* yp = y + ((size_t)r << 6) + (sub << 2);
    unsafeAtomicAdd(yp + 0, v * xv.x);
    unsafeAtomicAdd(yp + 1, v * xv.y);
    unsafeAtomicAdd(yp + 2, v * xv.z);
    unsafeAtomicAdd(yp + 3, v * xv.w);
}

__global__ void k_normalize(float* __restrict__ out, int nrows) {
    int row = blockIdx.x * 4 + (threadIdx.x >> 6);
    if (row >= nrows) return;
    int lane = threadIdx.x & 63;
    size_t idx = ((size_t)row << 6) + lane;
    float v = out[idx] * 0.25f;
    float s = v * v;
#pragma unroll
    for (int off = 32; off; off >>= 1) s += __shfl_xor(s, off);
    float norm = fmaxf(sqrtf(s), 1e-12f);
    out[idx] = v / norm;
}

// ---------------------------------------------------------------------------

extern "C" void kernel_launch(void* const* d_in, const int* in_sizes, int n_in,
                              void* d_out, int out_size, void* d_ws,
                              size_t ws_size, hipStream_t stream) {
    const int* m_rows = (const int*)d_in[0];
    const int* m_cols = (const int*)d_in[1];
    const float* m_vals = (const float*)d_in[2];
    const int* a_rows = (const int*)d_in[3];
    const int* a_cols = (const int*)d_in[4];
    const float* a_vals = (const float*)d_in[5];
    const float* m_emb = (const float*)d_in[6];
    const float* a_emb = (const float*)d_in[7];

    int ne_m = in_sizes[0];
    int ne_a = in_sizes[3];
    int nm = in_sizes[6] / EMB_DIM;
    int na = in_sizes[7] / EMB_DIM;

    size_t elems_m = (size_t)nm * EMB_DIM;
    int nmax = nm > na ? nm : na;
    float* out_m = (float*)d_out;
    float* out_a = out_m + elems_m;

    // ws layout: both ev arrays resident; fp16 buffers aliased per phase.
    char* w = (char*)d_ws;
    ull* ev_m = (ull*)w;            w += (size_t)ne_m * sizeof(ull);
    ull* ev_a = (ull*)w;            w += (size_t)ne_a * sizeof(ull);
    _Float16* x0h = (_Float16*)w;   w += (size_t)nmax * EMB_DIM * sizeof(_Float16);
    _Float16* buf0h = (_Float16*)w; w += (size_t)nmax * EMB_DIM * sizeof(_Float16);
    int* row_ptr_m = (int*)w;       w += ((size_t)nm + 1) * sizeof(int);
    int* row_pos_m = (int*)w;       w += (size_t)nm * sizeof(int);
    int* row_ptr_a = (int*)w;       w += ((size_t)na + 1) * sizeof(int);
    int* row_pos_a = (int*)w;       w += (size_t)na * sizeof(int);
    int* bsums = (int*)w;           w += 1024 * sizeof(int);
    size_t need = (size_t)(w - (char*)d_ws);

    if (ws_size >= need) {
        // ---- merged CSR build ----
        k_zero2<<<cdiv(nm + na, 256), 256, 0, stream>>>(row_pos_m, nm,
                                                        row_pos_a, na);
        k_hist2<<<cdiv((ne_m >> 2) + (ne_a >> 2) + 1, 256), 256, 0, stream>>>(
            m_rows, ne_m, row_pos_m, a_rows, ne_a, row_pos_a);
        int nsb_m = cdiv(nm, SCAN_E);
        k_scan1<<<nsb_m, SCAN_B, 0, stream>>>(row_pos_m, nm, row_ptr_m, bsums);
        k_scan2<<<1, 1024, 0, stream>>>(bsums, nsb_m);
        k_scan3<<<cdiv(nm, 256), 256, 0, stream>>>(row_ptr_m, row_pos_m, bsums,
                                                   nm, ne_m);
        int nsb_a = cdiv(na, SCAN_E);
        k_scan1<<<nsb_a, SCAN_B, 0, stream>>>(row_pos_a, na, row_ptr_a, bsums);
        k_scan2<<<1, 1024, 0, stream>>>(bsums, nsb_a);
        k_scan3<<<cdiv(na, 256), 256, 0, stream>>>(row_ptr_a, row_pos_a, bsums,
                                                   na, ne_a);
        unsigned pmul_m = (unsigned)(((unsigned long long)8 << 16) / (unsigned)nm);
        unsigned pmul_a = (unsigned)(((unsigned long long)8 << 16) / (unsigned)na);
        k_scatter2<<<2048, 256, 0, stream>>>(m_rows, m_cols, m_vals, ne_m,
                                             pmul_m, row_pos_m, ev_m, a_rows,
                                             a_cols, a_vals, ne_a, pmul_a,
                                             row_pos_a, ev_a, 1408);

        auto run_spmm = [&](ull* ev, int* row_ptr, const float* emb,
                            float* out, int n) {
            int nel = n * EMB_DIM;
            k_tohalf<<<cdiv(nel / 4, 256), 256, 0, stream>>>(emb, x0h, nel);
            int g = cdiv(n, 4);
            k_spmm_quad<true, false><<<g, 256, 0, stream>>>(
                ev, row_ptr, x0h, buf0h, out, emb, n);
            k_spmm_quad<false, false><<<g, 256, 0, stream>>>(
                ev, row_ptr, buf0h, x0h, out, nullptr, n);
            k_spmm_quad<false, true><<<g, 256, 0, stream>>>(
                ev, row_ptr, x0h, nullptr, out, nullptr, n);
        };
        run_spmm(ev_m, row_ptr_m, m_emb, out_m, nm);
        run_spmm(ev_a, row_ptr_a, a_emb, out_a, na);
        return;
    }

    // Fallback: round-0 atomic path.
    float* fb0 = (float*)d_ws;
    float* fb1 = fb0 + elems_m;
    auto run_atomic = [&](const int* rows, const int* cols, const float* vals,
                          const float* emb, float* out, int nrows,
                          int nedges) {
        size_t n = (size_t)nrows * EMB_DIM;
        int n4 = (int)(n / 4);
        int eg = cdiv(n4, 256);
        k_copy2<<<eg, 256, 0, stream>>>((const float4*)emb, (float4*)out,
                                        (float4*)fb0, n4);
        float* cur = fb0;
        float* nxt = fb1;
        int spmm_grid = cdiv((long long)nedges * 16, 256);
        for (int l = 0; l < 3; ++l) {
            k_zero<<<eg, 256, 0, stream>>>((float4*)nxt, n4);
            k_spmm_atomic<<<spmm_grid, 256, 0, stream>>>(rows, cols, vals, cur,
                                                         nxt, nedges);
            k_axpy<<<eg, 256, 0, stream>>>((float4*)out, (const float4*)nxt,
                                           n4);
            float* t = cur; cur = nxt; nxt = t;
        }
        k_normalize<<<cdiv(nrows, 4), 256, 0, stream>>>(out, nrows);
    };
    run_atomic(m_rows, m_cols, m_vals, m_emb, out_m, nm, ne_m);
    run_atomic(a_rows, a_cols, a_vals, a_emb, out_a, na, ne_a);
}